// Round 1
// baseline (50.151 us; speedup 1.0000x reference)
//
#include <hip/hip_runtime.h>
#include <hip/hip_bf16.h>

// Problem constants (reference: K=512, D=128, N=8192)
#define KC 512
#define DD 128
#define NP 8192

// ws layout: [0, 2KB): sumc2 (512 f32); [4KB, 4KB+256KB): CkT (128 x 512 f32)

// Prep kernel:
//   blocks 0..31  : transpose Ck (512x128) -> CkT (128x512)
//   block  32     : sumc2[k] = sum_d Ck[k][d]^2
//   blocks 33..65 : zero d_out (66048 floats)
__global__ __launch_bounds__(256) void kprep(const float* __restrict__ Ck,
                                             float* __restrict__ CkT,
                                             float* __restrict__ sumc2,
                                             float* __restrict__ out) {
    const int b = blockIdx.x;
    const int t = threadIdx.x;
    if (b < 32) {
        // 65536 elements; each block 2048, each thread 8 (write-coalesced over CkT)
        #pragma unroll
        for (int i = 0; i < 8; ++i) {
            const int idx = b * 2048 + i * 256 + t;   // flat index into CkT (d*512 + k)
            const int d = idx >> 9;
            const int k = idx & 511;
            CkT[idx] = Ck[k * DD + d];
        }
    } else if (b == 32) {
        #pragma unroll
        for (int c = 0; c < 2; ++c) {
            const int k = t + c * 256;
            const float4* row = (const float4*)(Ck + k * DD);
            float s = 0.f;
            #pragma unroll
            for (int i = 0; i < 32; ++i) {
                const float4 v = row[i];
                s += v.x * v.x + v.y * v.y + v.z * v.z + v.w * v.w;
            }
            sumc2[k] = s;
        }
    } else {
        const int base = (b - 33) * 2048 + t;
        #pragma unroll
        for (int i = 0; i < 8; ++i) {
            const int idx = base + i * 256;
            if (idx < KC * DD + KC) out[idx] = 0.f;
        }
    }
}

// Main kernel: grid 256 blocks x 256 threads. Each block: 32 points vs all 512 centroids.
// Thread micro-tile: 8 points x 8 centroids (64 fp32 accumulators).
//   lane = tid & 63 (centroid groups), wv = tid >> 6 (point group; wave-uniform).
//   Thread's centroids: {4*lane + j | j=0..3} U {256 + 4*lane + j | j=0..3}.
//   Thread's points:    {8*wv + i | i=0..7}.
// cst holds a 16-dim slice of CkT: cst[kk][k] -> lane-stride-16B ds_read_b128, conflict-free.
// xs reads are wave-uniform broadcasts (free).
__global__ __launch_bounds__(256, 1) void kmain(const float* __restrict__ X,
                                                const float* __restrict__ CkT,
                                                const float* __restrict__ sumc2,
                                                float* __restrict__ out) {
    __shared__ __align__(16) float xs[32 * DD];      // 16 KB
    __shared__ __align__(16) float cst[16 * KC];     // 32 KB
    __shared__ int win[32];

    const int tid  = threadIdx.x;
    const int lane = tid & 63;
    const int wv   = tid >> 6;
    const int p0   = blockIdx.x * 32;

    // stage x tile (32 x 128 fp32, linear, coalesced)
    {
        const float4* Xv = (const float4*)(X + p0 * DD);
        float4* xv = (float4*)xs;
        #pragma unroll
        for (int i = 0; i < 4; ++i) xv[tid + 256 * i] = Xv[tid + 256 * i];
    }

    float acc[8][8];
    #pragma unroll
    for (int i = 0; i < 8; ++i)
        #pragma unroll
        for (int j = 0; j < 8; ++j) acc[i][j] = 0.f;

    // K-loop over 8 slices of 16 dims
    for (int s = 0; s < 8; ++s) {
        __syncthreads();
        {   // stage 16x512 slice of CkT (contiguous in global), linear into LDS
            const float4* Cv = (const float4*)(CkT + s * 16 * KC);
            float4* cv = (float4*)cst;
            #pragma unroll
            for (int i = 0; i < 8; ++i) cv[tid + 256 * i] = Cv[tid + 256 * i];
        }
        __syncthreads();

        #pragma unroll
        for (int kk4 = 0; kk4 < 4; ++kk4) {
            float4 xf[8];
            #pragma unroll
            for (int i = 0; i < 8; ++i)
                xf[i] = *(const float4*)&xs[(8 * wv + i) * DD + s * 16 + kk4 * 4];
            #pragma unroll
            for (int kk = 0; kk < 4; ++kk) {
                const float4 c0 = *(const float4*)&cst[(kk4 * 4 + kk) * KC + 4 * lane];
                const float4 c1 = *(const float4*)&cst[(kk4 * 4 + kk) * KC + 256 + 4 * lane];
                #pragma unroll
                for (int i = 0; i < 8; ++i) {
                    const float xv = (&xf[i].x)[kk];
                    acc[i][0] = fmaf(xv, c0.x, acc[i][0]);
                    acc[i][1] = fmaf(xv, c0.y, acc[i][1]);
                    acc[i][2] = fmaf(xv, c0.z, acc[i][2]);
                    acc[i][3] = fmaf(xv, c0.w, acc[i][3]);
                    acc[i][4] = fmaf(xv, c1.x, acc[i][4]);
                    acc[i][5] = fmaf(xv, c1.y, acc[i][5]);
                    acc[i][6] = fmaf(xv, c1.z, acc[i][6]);
                    acc[i][7] = fmaf(xv, c1.w, acc[i][7]);
                }
            }
        }
    }

    // per-thread argmin over its 8 centroids (ascending index order, strict <)
    float bestv[8];
    int   besti[8];
    #pragma unroll
    for (int i = 0; i < 8; ++i) { bestv[i] = 3.4e38f; besti[i] = 0; }
    #pragma unroll
    for (int j = 0; j < 8; ++j) {
        const int cent = (j < 4) ? (4 * lane + j) : (256 + 4 * lane + (j - 4));
        const float s2 = sumc2[cent];
        #pragma unroll
        for (int i = 0; i < 8; ++i) {
            const float v = fmaf(-2.f, acc[i][j], s2);   // monotonic proxy for d2
            if (v < bestv[i]) { bestv[i] = v; besti[i] = cent; }
        }
    }
    // wave butterfly reduction, tie-break on smaller index (jnp.argmin = first min)
    #pragma unroll
    for (int off = 1; off < 64; off <<= 1) {
        #pragma unroll
        for (int i = 0; i < 8; ++i) {
            const float ov = __shfl_xor(bestv[i], off);
            const int   oi = __shfl_xor(besti[i], off);
            if (ov < bestv[i] || (ov == bestv[i] && oi < besti[i])) {
                bestv[i] = ov; besti[i] = oi;
            }
        }
    }
    if (lane == 0) {
        #pragma unroll
        for (int i = 0; i < 8; ++i) win[8 * wv + i] = besti[i];
    }
    __syncthreads();

    // fused scatter: segment-sum this block's 32 points (lanes hit distinct addresses)
    #pragma unroll
    for (int i = 0; i < 16; ++i) {
        const int flat = tid + 256 * i;     // 0..4095 = p*128 + d
        const int p = flat >> 7;
        const int d = flat & 127;
        atomicAdd(&out[win[p] * DD + d], xs[flat]);
    }
    if (tid < 32) atomicAdd(&out[KC * DD + win[tid]], 1.0f);
}

extern "C" void kernel_launch(void* const* d_in, const int* in_sizes, int n_in,
                              void* d_out, int out_size, void* d_ws, size_t ws_size,
                              hipStream_t stream) {
    const float* locF = (const float*)d_in[0];
    const float* Ck   = (const float*)d_in[1];
    float* out   = (float*)d_out;
    float* sumc2 = (float*)d_ws;
    float* CkT   = (float*)((char*)d_ws + 4096);

    hipLaunchKernelGGL(kprep, dim3(66), dim3(256), 0, stream, Ck, CkT, sumc2, out);
    hipLaunchKernelGGL(kmain, dim3(256), dim3(256), 0, stream, locF, CkT, sumc2, out);
}

// Round 2
// 42.897 us; speedup vs baseline: 1.1691x; 1.1691x over previous
//
#include <hip/hip_runtime.h>
#include <hip/hip_bf16.h>

// Problem constants (reference: K=512, D=128, N=8192)
#define KC 512
#define DD 128
#define NP 8192

// ws layout: [0, 2KB): sumc2 (512 f32); [4KB, 4KB+256KB): CkT (128 x 512 f32)

// async global->LDS, 16B per lane. dest = wave-uniform base + lane*16.
__device__ __forceinline__ void gload_lds16(const float* g, float* l) {
    __builtin_amdgcn_global_load_lds(
        (const __attribute__((address_space(1))) void*)(uintptr_t)g,
        (__attribute__((address_space(3))) void*)(uintptr_t)l,
        16, 0, 0);
}

// Prep kernel:
//   blocks 0..31  : transpose Ck (512x128) -> CkT (128x512)
//   block  32     : sumc2[k] = sum_d Ck[k][d]^2
//   blocks 33..65 : zero d_out (66048 floats)
__global__ __launch_bounds__(256) void kprep(const float* __restrict__ Ck,
                                             float* __restrict__ CkT,
                                             float* __restrict__ sumc2,
                                             float* __restrict__ out) {
    const int b = blockIdx.x;
    const int t = threadIdx.x;
    if (b < 32) {
        #pragma unroll
        for (int i = 0; i < 8; ++i) {
            const int idx = b * 2048 + i * 256 + t;   // flat index into CkT (d*512 + k)
            const int d = idx >> 9;
            const int k = idx & 511;
            CkT[idx] = Ck[k * DD + d];
        }
    } else if (b == 32) {
        #pragma unroll
        for (int c = 0; c < 2; ++c) {
            const int k = t + c * 256;
            const float4* row = (const float4*)(Ck + k * DD);
            float s = 0.f;
            #pragma unroll
            for (int i = 0; i < 32; ++i) {
                const float4 v = row[i];
                s += v.x * v.x + v.y * v.y + v.z * v.z + v.w * v.w;
            }
            sumc2[k] = s;
        }
    } else {
        const int base = (b - 33) * 2048 + t;
        #pragma unroll
        for (int i = 0; i < 8; ++i) {
            const int idx = base + i * 256;
            if (idx < KC * DD + KC) out[idx] = 0.f;
        }
    }
}

// Main kernel: grid 512 blocks x 256 threads. Block: 16 points vs all 512 centroids,
// D split across wave-pairs:
//   wv = tid>>6 (0..3); h = wv>>1 selects dim-half (0: d 0..63, 1: d 64..127)
//   wl = wv&1 selects point group (points 8*wl .. 8*wl+7)
// Thread micro-tile: 8 points x 8 centroids over its 64 dims (partial dots).
// End: half-1 waves dump acc to LDS, half-0 waves combine, argmin, scatter.
// Centroid slices (8 dims x 512) double-buffered via global_load_lds + counted vmcnt.
__global__ __launch_bounds__(256, 2) void kmain(const float* __restrict__ X,
                                                const float* __restrict__ CkT,
                                                const float* __restrict__ sumc2,
                                                float* __restrict__ out) {
    __shared__ __align__(16) float xs[16 * DD];          // 8 KB
    __shared__ __align__(16) float cst[2][2][8 * KC];    // 64 KB [buf][half][d*512+k]
    __shared__ int win[16];

    const int tid  = threadIdx.x;
    const int lane = tid & 63;
    const int wv   = tid >> 6;
    const int h    = wv >> 1;
    const int wl   = wv & 1;
    const int p0   = blockIdx.x * 16;

    // prologue: stage x tile (16x128 = 2048 floats, 2 issues/thread)
    const float* Xg = X + p0 * DD;
    #pragma unroll
    for (int j = 0; j < 2; ++j) {
        const int unit = (wv * 2 + j) * 64;               // 16B-unit base for this wave-issue
        gload_lds16(Xg + (unit + lane) * 4, &xs[unit * 4]);
    }

    // stage one 8-dim slice of this half's centroids into cst[b][h]
    auto STAGE = [&](int t, int b) {
        const float* src = CkT + (h * 64 + t * 8) * KC;   // 4096 contiguous floats
        float* dst = &cst[b][h][0];
        #pragma unroll
        for (int j = 0; j < 8; ++j) {
            const int chunk = (wl * 8 + j) * 256;         // floats
            gload_lds16(src + chunk + lane * 4, dst + chunk);
        }
    };
    STAGE(0, 0);   // outstanding: 2 (xs) + 8 = 10

    float acc[8][8];
    #pragma unroll
    for (int i = 0; i < 8; ++i)
        #pragma unroll
        for (int j = 0; j < 8; ++j) acc[i][j] = 0.f;

    for (int t = 0; t < 8; ++t) {
        const int b = t & 1;
        if (t < 7) {
            STAGE(t + 1, b ^ 1);                           // 8 more in flight
            asm volatile("s_waitcnt vmcnt(8)" ::: "memory");  // cur buf (+xs) landed
        } else {
            asm volatile("s_waitcnt vmcnt(0)" ::: "memory");
        }
        __builtin_amdgcn_s_barrier();                      // A: all waves' cur writes done
        __builtin_amdgcn_sched_barrier(0);

        const float* cb = &cst[b][h][0];
        const int dbase = h * 64 + t * 8;
        #pragma unroll
        for (int kk4 = 0; kk4 < 2; ++kk4) {
            float4 xf[8];
            #pragma unroll
            for (int i = 0; i < 8; ++i)
                xf[i] = *(const float4*)&xs[(8 * wl + i) * DD + dbase + kk4 * 4];
            #pragma unroll
            for (int kk = 0; kk < 4; ++kk) {
                const float4 c0 = *(const float4*)&cb[(kk4 * 4 + kk) * KC + 4 * lane];
                const float4 c1 = *(const float4*)&cb[(kk4 * 4 + kk) * KC + 256 + 4 * lane];
                #pragma unroll
                for (int i = 0; i < 8; ++i) {
                    const float xv = (&xf[i].x)[kk];
                    acc[i][0] = fmaf(xv, c0.x, acc[i][0]);
                    acc[i][1] = fmaf(xv, c0.y, acc[i][1]);
                    acc[i][2] = fmaf(xv, c0.z, acc[i][2]);
                    acc[i][3] = fmaf(xv, c0.w, acc[i][3]);
                    acc[i][4] = fmaf(xv, c1.x, acc[i][4]);
                    acc[i][5] = fmaf(xv, c1.y, acc[i][5]);
                    acc[i][6] = fmaf(xv, c1.z, acc[i][6]);
                    acc[i][7] = fmaf(xv, c1.w, acc[i][7]);
                }
            }
        }
        __builtin_amdgcn_sched_barrier(0);
        __builtin_amdgcn_s_barrier();                      // B: cur fully read before t+2 overwrites
        __builtin_amdgcn_sched_barrier(0);
    }

    // ---- combine the two dim-halves (half-1 -> LDS -> half-0 adds) ----
    float4* ex = (float4*)&cst[0][0][0];                   // 16 x 128 float4 = 32 KB
    const int tl = tid & 127;
    if (h == 1) {
        #pragma unroll
        for (int i = 0; i < 8; ++i) {
            ex[(2 * i) * 128 + tl]     = make_float4(acc[i][0], acc[i][1], acc[i][2], acc[i][3]);
            ex[(2 * i + 1) * 128 + tl] = make_float4(acc[i][4], acc[i][5], acc[i][6], acc[i][7]);
        }
    }
    __syncthreads();
    if (h == 0) {
        #pragma unroll
        for (int i = 0; i < 8; ++i) {
            const float4 a0 = ex[(2 * i) * 128 + tl];
            const float4 a1 = ex[(2 * i + 1) * 128 + tl];
            acc[i][0] += a0.x; acc[i][1] += a0.y; acc[i][2] += a0.z; acc[i][3] += a0.w;
            acc[i][4] += a1.x; acc[i][5] += a1.y; acc[i][6] += a1.z; acc[i][7] += a1.w;
        }
        // per-thread argmin over its 8 centroids (ascending index, strict <)
        float bestv[8];
        int   besti[8];
        #pragma unroll
        for (int i = 0; i < 8; ++i) { bestv[i] = 3.4e38f; besti[i] = 0; }
        #pragma unroll
        for (int j = 0; j < 8; ++j) {
            const int cent = (j < 4) ? (4 * lane + j) : (256 + 4 * lane + (j - 4));
            const float s2 = sumc2[cent];
            #pragma unroll
            for (int i = 0; i < 8; ++i) {
                const float v = fmaf(-2.f, acc[i][j], s2);   // monotonic proxy for d2
                if (v < bestv[i]) { bestv[i] = v; besti[i] = cent; }
            }
        }
        // wave butterfly, tie-break on smaller index (jnp.argmin = first min)
        #pragma unroll
        for (int off = 1; off < 64; off <<= 1) {
            #pragma unroll
            for (int i = 0; i < 8; ++i) {
                const float ov = __shfl_xor(bestv[i], off);
                const int   oi = __shfl_xor(besti[i], off);
                if (ov < bestv[i] || (ov == bestv[i] && oi < besti[i])) {
                    bestv[i] = ov; besti[i] = oi;
                }
            }
        }
        if (lane == 0) {
            #pragma unroll
            for (int i = 0; i < 8; ++i) win[8 * wl + i] = besti[i];
        }
    }
    __syncthreads();

    // fused scatter: 16 points x 128 dims (lanes hit distinct addresses)
    #pragma unroll
    for (int i = 0; i < 8; ++i) {
        const int flat = tid + 256 * i;     // p*128 + d
        const int p = flat >> 7;
        const int d = flat & 127;
        atomicAdd(&out[win[p] * DD + d], xs[flat]);
    }
    if (tid < 16) atomicAdd(&out[KC * DD + win[tid]], 1.0f);
}

extern "C" void kernel_launch(void* const* d_in, const int* in_sizes, int n_in,
                              void* d_out, int out_size, void* d_ws, size_t ws_size,
                              hipStream_t stream) {
    const float* locF = (const float*)d_in[0];
    const float* Ck   = (const float*)d_in[1];
    float* out   = (float*)d_out;
    float* sumc2 = (float*)d_ws;
    float* CkT   = (float*)((char*)d_ws + 4096);

    hipLaunchKernelGGL(kprep, dim3(66), dim3(256), 0, stream, Ck, CkT, sumc2, out);
    hipLaunchKernelGGL(kmain, dim3(512), dim3(256), 0, stream, locF, CkT, sumc2, out);
}